// Round 5
// baseline (191.370 us; speedup 1.0000x reference)
//
#include <hip/hip_runtime.h>
#include <cfloat>

typedef _Float16 f16x8 __attribute__((ext_vector_type(8)));
typedef _Float16 f16x4 __attribute__((ext_vector_type(4)));
typedef float    f32x4 __attribute__((ext_vector_type(4)));

#define N_TOK 262144
#define DIM   64
#define KCB   512
#define TAU_T 0.0625f      // flag threshold in half-distance units (dist 0.125)
#define FIXS  262144.0f    // 2^18 fixed-point scale (exact pow2 f32 multiply)

// swizzled byte offset of (code, dim-byte db) in the f16 codebook image:
// within a 128B row, XOR 16B-slot bits with code&7  -> 2-way LDS conflicts max
__device__ __forceinline__ int swz(int code, int db) {
    return code * 128 + (db ^ ((code & 7) << 4));
}

// ---------------------------------------------------------------------------
// prep: qneg[k] = -0.5*||v_k||^2 (f32), qd[k] = ||v_k||^2 (f64), and the
// pre-swizzled f16 codebook image vqf16 (64 KB, L2-resident).
// 16 blocks x 512 thr; 16 lanes per code row (coalesced).
// ---------------------------------------------------------------------------
__global__ __launch_bounds__(512) void prep_kernel(const float* __restrict__ vq,
        float* __restrict__ qneg, double* __restrict__ qd,
        char* __restrict__ vqf16) {
    const int tid  = threadIdx.x;
    const int code = blockIdx.x * 32 + (tid >> 4);
    const int c4   = tid & 15;
    float4 g = *(const float4*)(vq + (size_t)code * DIM + c4 * 4);
    double s = 0.0;
    s = fma((double)g.x, (double)g.x, s);
    s = fma((double)g.y, (double)g.y, s);
    s = fma((double)g.z, (double)g.z, s);
    s = fma((double)g.w, (double)g.w, s);
#pragma unroll
    for (int sh = 1; sh < 16; sh <<= 1) s += __shfl_xor(s, sh, 64);
    if (c4 == 0) { qd[code] = s; qneg[code] = -(float)(0.5 * s); }
    f16x4 h = {(_Float16)g.x, (_Float16)g.y, (_Float16)g.z, (_Float16)g.w};
    *(f16x4*)(vqf16 + swz(code, c4 * 8)) = h;
}

// ---------------------------------------------------------------------------
// MFMA argmin: acc = -q/2 + x_hi.v + x_lo.v  (argmax acc == argmin dist).
// 512 thr = 8 waves; 256 tokens/block (32/wave, tt=2 subtiles).
// A = x (tokens, hi/lo f16 frags in REGISTERS, loaded once from global);
// B = v chunk (64 codes) staged f16 in LDS dbuf from the pre-swizzled image.
// D: row = token (grp*4+j), col = code (li)  ->  bias is scalar per tile.
// ---------------------------------------------------------------------------
__global__ __launch_bounds__(512, 4) void argmin_mfma_kernel(
    const float* __restrict__ x, const float* __restrict__ vq,
    const float* __restrict__ qneg, int* __restrict__ idx_out,
    int* __restrict__ flag_cnt, int* __restrict__ flag_list,
    float* __restrict__ quant, int* __restrict__ counts,
    const char* __restrict__ vqf16)
{
    __shared__ _Float16 vh[2][4096];     // 2 x 8 KB dbuf
    __shared__ float    qneg_lds[KCB];   // 2 KB
    __shared__ int      idx_lds[256];
    __shared__ int      hist[KCB];

    const int tid = threadIdx.x;
    const int m0  = blockIdx.x * 256;
    const int lane = tid & 63, w = tid >> 6;
    const int grp = lane >> 4, li = lane & 15;

    hist[tid] = 0;
    qneg_lds[tid] = qneg[tid];

    // x -> A-frags in registers, exact hi/lo f16 split
    f16x8 ah[2][2], al[2][2];
#pragma unroll
    for (int tt = 0; tt < 2; ++tt)
#pragma unroll
        for (int kk = 0; kk < 2; ++kk) {
            const float* p = x + (size_t)(m0 + w * 32 + tt * 16 + li) * DIM
                           + kk * 32 + grp * 8;
            float4 g0 = *(const float4*)p;
            float4 g1 = *(const float4*)(p + 4);
            float xs[8] = {g0.x, g0.y, g0.z, g0.w, g1.x, g1.y, g1.z, g1.w};
            f16x8 hi, lo;
#pragma unroll
            for (int e = 0; e < 8; ++e) {
                _Float16 h = (_Float16)xs[e];
                hi[e] = h;
                lo[e] = (_Float16)(xs[e] - (float)h);
            }
            ah[tt][kk] = hi; al[tt][kk] = lo;
        }

    // stage chunk 0 (image is pre-swizzled: linear copy)
    {
        int4 v = *(const int4*)(vqf16 + tid * 16);
        *(int4*)((char*)vh[0] + tid * 16) = v;
    }

    float m1[8], m2[8]; int i1[8];
#pragma unroll
    for (int s = 0; s < 8; ++s) { m1[s] = -FLT_MAX; m2[s] = -FLT_MAX; i1[s] = 0; }

    for (int ch = 0; ch < 8; ++ch) {
        const int cur = ch & 1;
        __syncthreads();                       // buf[cur] staged, prev reads done
        int4 pre;
        if (ch < 7)                            // T14: issue next-chunk load early
            pre = *(const int4*)(vqf16 + (ch + 1) * 8192 + tid * 16);

        const char* vb = (const char*)vh[cur];
#pragma unroll
        for (int tc = 0; tc < 4; ++tc) {
            const int rowb = (tc * 16 + li) * 128;
            const int sw   = (li & 7) << 4;
            f16x8 vf0 = *(const f16x8*)(vb + rowb + ((grp * 16) ^ sw));
            f16x8 vf1 = *(const f16x8*)(vb + rowb + ((64 + grp * 16) ^ sw));
            float qv = qneg_lds[ch * 64 + tc * 16 + li];
            f32x4 acc0 = {qv, qv, qv, qv};
            f32x4 acc1 = {qv, qv, qv, qv};
            acc0 = __builtin_amdgcn_mfma_f32_16x16x32_f16(ah[0][0], vf0, acc0, 0, 0, 0);
            acc1 = __builtin_amdgcn_mfma_f32_16x16x32_f16(ah[1][0], vf0, acc1, 0, 0, 0);
            acc0 = __builtin_amdgcn_mfma_f32_16x16x32_f16(al[0][0], vf0, acc0, 0, 0, 0);
            acc1 = __builtin_amdgcn_mfma_f32_16x16x32_f16(al[1][0], vf0, acc1, 0, 0, 0);
            acc0 = __builtin_amdgcn_mfma_f32_16x16x32_f16(ah[0][1], vf1, acc0, 0, 0, 0);
            acc1 = __builtin_amdgcn_mfma_f32_16x16x32_f16(ah[1][1], vf1, acc1, 0, 0, 0);
            acc0 = __builtin_amdgcn_mfma_f32_16x16x32_f16(al[0][1], vf1, acc0, 0, 0, 0);
            acc1 = __builtin_amdgcn_mfma_f32_16x16x32_f16(al[1][1], vf1, acc1, 0, 0, 0);

            const int idv = ch * 64 + tc * 16 + li;
#pragma unroll
            for (int j = 0; j < 4; ++j) {       // tt = 0
                float t = acc0[j];
                bool c = t > m1[j];
                m2[j] = fmaxf(m2[j], c ? m1[j] : t);
                m1[j] = c ? t : m1[j];
                i1[j] = c ? idv : i1[j];
            }
#pragma unroll
            for (int j = 0; j < 4; ++j) {       // tt = 1
                int s = 4 + j;
                float t = acc1[j];
                bool c = t > m1[s];
                m2[s] = fmaxf(m2[s], c ? m1[s] : t);
                m1[s] = c ? t : m1[s];
                i1[s] = c ? idv : i1[s];
            }
        }
        if (ch < 7)                            // stage into the freed buffer
            *(int4*)((char*)vh[cur ^ 1] + tid * 16) = pre;
    }

    // reduce across the 16 code-lanes per token; ties -> smaller code index
#pragma unroll
    for (int s = 0; s < 8; ++s) {
        float v1 = m1[s], v2 = m2[s];
        int ix = i1[s];
#pragma unroll
        for (int sh = 1; sh < 16; sh <<= 1) {
            float o1 = __shfl_xor(v1, sh, 64);
            float o2 = __shfl_xor(v2, sh, 64);
            int   oi = __shfl_xor(ix, sh, 64);
            v2 = fmaxf(v2, fmaxf(o2, fminf(v1, o1)));
            bool c = (o1 > v1) || (o1 == v1 && oi < ix);
            v1 = c ? o1 : v1;
            ix = c ? oi : ix;
        }
        if (li == 0) {
            int tokloc = w * 32 + (s >> 2) * 16 + grp * 4 + (s & 3);
            idx_lds[tokloc] = ix;
            idx_out[m0 + tokloc] = ix;
            if (v1 - v2 < TAU_T) {
                int p = atomicAdd(flag_cnt, 1);
                flag_list[p] = m0 + tokloc;
            }
        }
    }
    __syncthreads();

    if (tid < 256) atomicAdd(&hist[idx_lds[tid]], 1);

    // quantized gather (refine later overwrites flagged rows)
#pragma unroll
    for (int jj = 0; jj < 8; ++jj) {
        int id = tid + jj * 512;
        int row = id >> 4, c4 = id & 15;
        int k = idx_lds[row];
        float4 v = *(const float4*)(vq + (size_t)k * DIM + c4 * 4);
        *(float4*)(quant + (size_t)(m0 + row) * DIM + c4 * 4) = v;
    }
    __syncthreads();
    if (hist[tid] > 0) atomicAdd(&counts[tid], hist[tid]);
}

// ---------------------------------------------------------------------------
// Exact fp64 re-argmin of flagged tokens (validated).  Patches counts[] on
// index flips.  vq staged fp32 in LDS (stride 68 floats, conflict-free b128).
// ---------------------------------------------------------------------------
__global__ __launch_bounds__(256) void refine_kernel(
    const float* __restrict__ x, const float* __restrict__ vq,
    const double* __restrict__ qd,
    const int* __restrict__ flag_cnt, const int* __restrict__ flag_list,
    int* __restrict__ idx_out, float* __restrict__ quant,
    int* __restrict__ counts)
{
    __shared__ float vql[KCB * 68];   // 136 KB
    const int cnt = *flag_cnt;
    if (cnt <= 0) return;
    const int tid = threadIdx.x;
#pragma unroll
    for (int j = 0; j < 32; ++j) {
        int id = tid + j * 256;
        int c = id >> 4, dq = id & 15;
        float4 g = *(const float4*)(vq + (size_t)c * DIM + dq * 4);
        *(float4*)&vql[(c * 17 + dq) * 4] = g;
    }
    __syncthreads();
    const int lane = tid & 63, w = tid >> 6;

    for (int fi = blockIdx.x * 4 + w; fi < cnt; fi += 1024) {
        int token = flag_list[fi];
        const float* xr = x + (size_t)token * DIM;
        double xd[DIM];
#pragma unroll
        for (int dq = 0; dq < 16; ++dq) {
            float4 g = *(const float4*)(xr + dq * 4);
            xd[dq * 4 + 0] = (double)g.x;
            xd[dq * 4 + 1] = (double)g.y;
            xd[dq * 4 + 2] = (double)g.z;
            xd[dq * 4 + 3] = (double)g.w;
        }
        double best = DBL_MAX; int bc = 0;
#pragma unroll 1
        for (int jj = 0; jj < 8; ++jj) {
            int c = lane + jj * 64;
            double s = 0.0;
#pragma unroll
            for (int dq = 0; dq < 16; ++dq) {
                float4 v = *(const float4*)&vql[(c * 17 + dq) * 4];
                s = fma(xd[dq * 4 + 0], (double)v.x, s);
                s = fma(xd[dq * 4 + 1], (double)v.y, s);
                s = fma(xd[dq * 4 + 2], (double)v.z, s);
                s = fma(xd[dq * 4 + 3], (double)v.w, s);
            }
            double dist = qd[c] - 2.0 * s;
            if (dist < best) { best = dist; bc = c; }
        }
#pragma unroll
        for (int sh = 1; sh < 64; sh <<= 1) {
            double ob = __shfl_xor(best, sh, 64);
            int    oc = __shfl_xor(bc, sh, 64);
            bool c = (ob < best) || (ob == best && oc < bc);
            best = c ? ob : best;
            bc   = c ? oc : bc;
        }
        if (lane == 0) {
            int old = idx_out[token];
            if (old != bc) {
                idx_out[token] = bc;
                atomicAdd(&counts[old], -1);
                atomicAdd(&counts[bc], 1);
            }
        }
        if (lane < 16) {
            float4 v = *(const float4*)&vql[(bc * 17 + lane) * 4];
            *(float4*)(quant + (size_t)token * DIM + lane * 4) = v;
        }
    }
}

// ---------------------------------------------------------------------------
// Exclusive scan of counts -> cursor; EMA for centroid_n output.
// ---------------------------------------------------------------------------
__global__ __launch_bounds__(512) void scan_ema_kernel(
    const int* __restrict__ counts, int* __restrict__ cursor,
    const float* __restrict__ cn_old, float* __restrict__ out_cn)
{
    __shared__ int s[KCB];
    const int tid = threadIdx.x;
    int my = counts[tid];
    s[tid] = my;
    __syncthreads();
    for (int off = 1; off < KCB; off <<= 1) {
        int v = s[tid];
        int a = (tid >= off) ? s[tid - off] : 0;
        __syncthreads();
        s[tid] = v + a;
        __syncthreads();
    }
    cursor[tid] = s[tid] - my;
    out_cn[tid] = cn_old[tid] * 0.99f + (float)my * 0.01f;
}

// ---------------------------------------------------------------------------
// Counting-sort scatter: LDS-local histogram, one global atomic per
// (block,code), packed (k<<18 | t).
// ---------------------------------------------------------------------------
__global__ __launch_bounds__(512) void scatter_kernel(
    const int* __restrict__ idx, int* __restrict__ cursor,
    int* __restrict__ sorted)
{
    __shared__ int lhist[KCB];
    __shared__ int lbase[KCB];
    const int tid = threadIdx.x;
    const int t0 = blockIdx.x * 1024;

    lhist[tid] = 0;
    __syncthreads();
    int k0 = idx[t0 + tid];
    int k1 = idx[t0 + 512 + tid];
    atomicAdd(&lhist[k0], 1);
    atomicAdd(&lhist[k1], 1);
    __syncthreads();
    int h = lhist[tid];
    lbase[tid] = (h > 0) ? atomicAdd(&cursor[tid], h) : 0;
    __syncthreads();
    lhist[tid] = 0;
    __syncthreads();
    int s0 = atomicAdd(&lhist[k0], 1);
    sorted[lbase[k0] + s0] = (k0 << 18) | (t0 + tid);
    int s1 = atomicAdd(&lhist[k1], 1);
    sorted[lbase[k1] + s1] = (k1 << 18) | (t0 + 512 + tid);
}

// ---------------------------------------------------------------------------
// Gather-reduce over sorted entries; int64 fixed-point, order-independent.
// ---------------------------------------------------------------------------
__global__ __launch_bounds__(256) void gather_kernel(
    const float* __restrict__ x, const int* __restrict__ sorted,
    unsigned long long* __restrict__ gsum)
{
    __shared__ int le[256];
    const int tid = threadIdx.x;
    le[tid] = sorted[blockIdx.x * 256 + tid];
    __syncthreads();
    const int lane = tid & 63, w = tid >> 6;
    const int base = w * 64;

    int e = le[base];
    int kc = e >> 18, t = e & 0x3FFFF;
    float v = x[(size_t)t * DIM + lane];
    int kp = kc;
    long long acc = 0;
#pragma unroll 4
    for (int i = 1; i < 64; ++i) {
        int e1 = le[base + i];
        int k1 = e1 >> 18, t1 = e1 & 0x3FFFF;
        float v1 = x[(size_t)t1 * DIM + lane];
        if (kc != kp) {
            atomicAdd(&gsum[kp * DIM + lane], (unsigned long long)acc);
            acc = 0; kp = kc;
        }
        acc += (long long)rintf(v * FIXS);
        kc = k1; v = v1;
    }
    if (kc != kp) {
        atomicAdd(&gsum[kp * DIM + lane], (unsigned long long)acc);
        acc = 0; kp = kc;
    }
    acc += (long long)rintf(v * FIXS);
    atomicAdd(&gsum[kp * DIM + lane], (unsigned long long)acc);
}

// ---------------------------------------------------------------------------
// Finalize: EMA + division for centroid_sum and vq outputs.
// ---------------------------------------------------------------------------
__global__ __launch_bounds__(512) void finalize_kernel(
    const unsigned long long* __restrict__ gsum,
    const float* __restrict__ cs_old, const float* __restrict__ out_cn,
    float* __restrict__ out_vq, float* __restrict__ out_cs)
{
    int gid = blockIdx.x * 512 + threadIdx.x;
    if (gid >= KCB * DIM) return;
    int k = gid >> 6;
    long long g = (long long)gsum[gid];
    float scs = (float)((double)g * (1.0 / 262144.0));
    float ncs = cs_old[gid] * 0.99f + scs * 0.01f;
    out_cs[gid] = ncs;
    out_vq[gid] = ncs / out_cn[k];
}

// ---------------------------------------------------------------------------
extern "C" void kernel_launch(void* const* d_in, const int* in_sizes, int n_in,
                              void* d_out, int out_size, void* d_ws, size_t ws_size,
                              hipStream_t stream)
{
    const float* x      = (const float*)d_in[0];
    const float* vq     = (const float*)d_in[1];
    const float* cs_old = (const float*)d_in[2];
    const float* cn_old = (const float*)d_in[3];

    float* out_q  = (float*)d_out;
    float* out_vq = out_q + (size_t)N_TOK * DIM;
    float* out_cs = out_vq + (size_t)KCB * DIM;
    float* out_cn = out_cs + (size_t)KCB * DIM;

    char* ws = (char*)d_ws;
    int*    idx       = (int*)(ws);                              // 1 MB
    int*    flag_list = (int*)(ws + (1 << 20));                  // 1 MB (reused as sorted)
    int*    sorted    = flag_list;                               // refine consumes flags first
    int*    flag_cnt  = (int*)(ws + (2 << 20));                  // 4 B
    float*  qneg      = (float*)(ws + (2 << 20) + 1024);         // 2 KB
    double* qd        = (double*)(ws + (2 << 20) + 4096);        // 4 KB
    int*    counts    = (int*)(ws + (2 << 20) + 8192);           // 2 KB  <- memset start
    int*    cursor    = (int*)(ws + (2 << 20) + 8192 + 2048);    // 2 KB
    unsigned long long* gsum =
        (unsigned long long*)(ws + (2 << 20) + 12288);           // 256 KB
    char*   vqf16     = ws + (2 << 20) + 12288 + 262144;         // 64 KB

    hipMemsetAsync(flag_cnt, 0, 4, stream);
    hipMemsetAsync(counts, 0, 2048 + 2048 + KCB * DIM * 8, stream);

    prep_kernel<<<16, 512, 0, stream>>>(vq, qneg, qd, vqf16);
    argmin_mfma_kernel<<<N_TOK / 256, 512, 0, stream>>>(x, vq, qneg, idx,
                                                        flag_cnt, flag_list,
                                                        out_q, counts, vqf16);
    refine_kernel<<<256, 256, 0, stream>>>(x, vq, qd, flag_cnt, flag_list,
                                           idx, out_q, counts);
    scan_ema_kernel<<<1, 512, 0, stream>>>(counts, cursor, cn_old, out_cn);
    scatter_kernel<<<N_TOK / 1024, 512, 0, stream>>>(idx, cursor, sorted);
    gather_kernel<<<N_TOK / 256, 256, 0, stream>>>(x, sorted, gsum);
    finalize_kernel<<<KCB * DIM / 512, 512, 0, stream>>>(gsum, cs_old, out_cn,
                                                         out_vq, out_cs);
}